// Round 9
// baseline (284.904 us; speedup 1.0000x reference)
//
#include <hip/hip_runtime.h>
#include <hip/hip_cooperative_groups.h>
#include <math.h>

// Problem dims
#define NB    2
#define LSEQ  256
#define HDIM  256
#define IDIM  512
#define NROW  512      // NB*LSEQ
#define NC    8        // scan chunks
#define TCH   32       // chunk length (NC*TCH == LSEQ)

typedef __attribute__((ext_vector_type(8))) short bf16x8;
typedef __attribute__((ext_vector_type(4))) float f32x4;

__device__ inline unsigned short f2b(float f) {
    unsigned u = __float_as_uint(f);
    return (unsigned short)((u + 0x7FFFu + ((u >> 16) & 1u)) >> 16);
}

// ---------------------------------------------------------------------------
// kcvt: convert x, W_in, conv_w (3 transposed planes), fused Wsg, bsg, W_out
// to bf16 staging buffers. Memory-bound, grid-stride.
// ---------------------------------------------------------------------------
__global__ __launch_bounds__(256) void kcvt(const float* __restrict__ x,
                                            const float* __restrict__ W_in,
                                            const float* __restrict__ conv_w,
                                            const float* __restrict__ W_ssm,
                                            const float* __restrict__ W_gate,
                                            const float* __restrict__ b_ssm,
                                            const float* __restrict__ b_gate,
                                            const float* __restrict__ W_out,
                                            unsigned short* __restrict__ xb,
                                            unsigned short* __restrict__ Wb,
                                            unsigned short* __restrict__ cwb,
                                            unsigned short* __restrict__ Wsgb,
                                            float* __restrict__ bsg,
                                            unsigned short* __restrict__ W_outb) {
    const int stride = gridDim.x * 256;
    const int t0 = blockIdx.x * 256 + threadIdx.x;
    for (int i = t0; i < 131072; i += stride) xb[i] = f2b(x[i]);
    for (int i = t0; i < 262144; i += stride) Wb[i] = f2b(W_in[i]);
    // cwb[k][o][i] = conv_w[o][i][k]; thread handles one (o,i), 3 planes
    for (int d = t0; d < 262144; d += stride) {
        const float* s = conv_w + (size_t)d * 3;
        cwb[d]          = f2b(s[0]);
        cwb[262144 + d] = f2b(s[1]);
        cwb[524288 + d] = f2b(s[2]);
    }
    // Wsgb rows: 0..1023 = W_ssm[512..1535]; 1024..1535 = W_gate[512..1023]
    for (int d = t0; d < 786432; d += stride) {
        int j = d >> 9, i = d & 511;
        float v = (j < 1024) ? W_ssm[(size_t)(512 + j) * 512 + i]
                             : W_gate[(size_t)(j - 512) * 512 + i];
        Wsgb[d] = f2b(v);
    }
    for (int j = t0; j < 1536; j += stride)
        bsg[j] = (j < 1024) ? b_ssm[512 + j] : b_gate[j - 512];
    for (int i = t0; i < 131072; i += stride) W_outb[i] = f2b(W_out[i]);
}

// ---------------------------------------------------------------------------
// k1: xp = x @ W_in^T (512x1024, K=256). Wave per 16x16 tile, no LDS.
// ---------------------------------------------------------------------------
__global__ __launch_bounds__(256) void k1_mfma(const unsigned short* __restrict__ xb,
                                               const unsigned short* __restrict__ Wb,
                                               float* __restrict__ xq_g,
                                               unsigned short* __restrict__ xkb) {
    const int t = threadIdx.x;
    const int w = blockIdx.x * 4 + (t >> 6);   // 0..2047
    const int lane = t & 63;
    const int mt = w >> 6, nt = w & 63;
    const int r0 = mt * 16, n0 = nt * 16;
    const int fr = lane & 15, fk = (lane >> 4) * 8;
    const unsigned short* ap = xb + (size_t)(r0 + fr) * HDIM + fk;
    const unsigned short* bp = Wb + (size_t)(n0 + fr) * HDIM + fk;
    f32x4 acc = {0.f, 0.f, 0.f, 0.f};
    #pragma unroll
    for (int k0 = 0; k0 < HDIM; k0 += 32) {
        bf16x8 av = *(const bf16x8*)(ap + k0);
        bf16x8 bv = *(const bf16x8*)(bp + k0);
        acc = __builtin_amdgcn_mfma_f32_16x16x32_bf16(av, bv, acc, 0, 0, 0);
    }
    const int orow = (lane >> 4) * 4;
    const int oc = n0 + fr;
    if (oc < IDIM) {
        #pragma unroll
        for (int j = 0; j < 4; ++j) {
            float v = acc[j];
            xq_g[(size_t)(r0 + orow + j) * IDIM + oc] =
                0.5f * v * (1.0f + erff(v * 0.70710678118654752f));
        }
    } else {
        #pragma unroll
        for (int j = 0; j < 4; ++j)
            xkb[(size_t)(r0 + orow + j) * IDIM + (oc - IDIM)] = f2b(acc[j]);
    }
}

// ---------------------------------------------------------------------------
// kxc: xc[r,o] = gelu_q[r,o] + conv_b[o] + sum_k xk[r+k-1,:]·cwb[k][o,:]
// ---------------------------------------------------------------------------
__global__ __launch_bounds__(256) void kxc_mfma(const unsigned short* __restrict__ xkb,
                                                const unsigned short* __restrict__ cwb,
                                                const float* __restrict__ xq_g,
                                                const float* __restrict__ conv_b,
                                                float* __restrict__ xc,
                                                unsigned short* __restrict__ xcb) {
    const int t = threadIdx.x;
    const int w = blockIdx.x * 4 + (t >> 6);   // 0..1023
    const int lane = t & 63;
    const int mt = w >> 5, nt = w & 31;
    const int r0 = mt * 16, o0 = nt * 16;
    const int fr = lane & 15, fk = (lane >> 4) * 8;
    const int g = r0 + fr;
    const int lo = r0 & ~255, hi = lo + 256;
    const bool okm = (g - 1 >= lo), okp = (g + 1 < hi);
    const unsigned short* am = xkb + (size_t)(g - 1) * IDIM + fk;
    const unsigned short* a0 = xkb + (size_t)g * IDIM + fk;
    const unsigned short* ap = xkb + (size_t)(g + 1) * IDIM + fk;
    const unsigned short* b0 = cwb + (size_t)(o0 + fr) * IDIM + fk;
    const unsigned short* b1 = b0 + 262144;
    const unsigned short* b2 = b0 + 524288;
    const bf16x8 zz = {0, 0, 0, 0, 0, 0, 0, 0};
    f32x4 acc = {0.f, 0.f, 0.f, 0.f};
    #pragma unroll
    for (int k0 = 0; k0 < IDIM; k0 += 32) {
        bf16x8 avm = okm ? *(const bf16x8*)(am + k0) : zz;
        bf16x8 av0 = *(const bf16x8*)(a0 + k0);
        bf16x8 avp = okp ? *(const bf16x8*)(ap + k0) : zz;
        bf16x8 bv0 = *(const bf16x8*)(b0 + k0);
        bf16x8 bv1 = *(const bf16x8*)(b1 + k0);
        bf16x8 bv2 = *(const bf16x8*)(b2 + k0);
        acc = __builtin_amdgcn_mfma_f32_16x16x32_bf16(avm, bv0, acc, 0, 0, 0);
        acc = __builtin_amdgcn_mfma_f32_16x16x32_bf16(av0, bv1, acc, 0, 0, 0);
        acc = __builtin_amdgcn_mfma_f32_16x16x32_bf16(avp, bv2, acc, 0, 0, 0);
    }
    const int orow = (lane >> 4) * 4;
    const int oc = o0 + fr;
    const float cb = conv_b[oc];
    #pragma unroll
    for (int j = 0; j < 4; ++j) {
        int r = r0 + orow + j;
        float v = acc[j] + xq_g[(size_t)r * IDIM + oc] + cb;
        xc[(size_t)r * IDIM + oc] = v;
        xcb[(size_t)r * IDIM + oc] = f2b(v);
    }
}

// ---------------------------------------------------------------------------
// k3f: fused ssm/gate GEMM + elementwise. Wave computes tiles (r0, s0),
// (r0, 512+s0), (r0, 1024+s0) of E sharing the A fragment, then:
//   Cw[r,s] = sigmoid(graw)*craw;  u[r,s] = xc[r,s]*dw*dw
// ---------------------------------------------------------------------------
__global__ __launch_bounds__(256) void k3f_mfma(const unsigned short* __restrict__ xcb,
                                                const unsigned short* __restrict__ Wsgb,
                                                const float* __restrict__ bsg,
                                                const float* __restrict__ xc,
                                                float* __restrict__ Cw,
                                                float* __restrict__ u) {
    const int t = threadIdx.x;
    const int w = blockIdx.x * 4 + (t >> 6);   // 0..1023
    const int lane = t & 63;
    const int mt = w >> 5, nt = w & 31;
    const int r0 = mt * 16, s0 = nt * 16;
    const int fr = lane & 15, fk = (lane >> 4) * 8;
    const unsigned short* ap = xcb + (size_t)(r0 + fr) * IDIM + fk;
    const unsigned short* b0 = Wsgb + (size_t)(s0 + fr) * IDIM + fk;
    const unsigned short* b1 = Wsgb + (size_t)(512 + s0 + fr) * IDIM + fk;
    const unsigned short* b2 = Wsgb + (size_t)(1024 + s0 + fr) * IDIM + fk;
    f32x4 ac0 = {0.f, 0.f, 0.f, 0.f};
    f32x4 ac1 = {0.f, 0.f, 0.f, 0.f};
    f32x4 ac2 = {0.f, 0.f, 0.f, 0.f};
    #pragma unroll
    for (int k0 = 0; k0 < IDIM; k0 += 32) {
        bf16x8 av  = *(const bf16x8*)(ap + k0);
        bf16x8 bv0 = *(const bf16x8*)(b0 + k0);
        bf16x8 bv1 = *(const bf16x8*)(b1 + k0);
        bf16x8 bv2 = *(const bf16x8*)(b2 + k0);
        ac0 = __builtin_amdgcn_mfma_f32_16x16x32_bf16(av, bv0, ac0, 0, 0, 0);
        ac1 = __builtin_amdgcn_mfma_f32_16x16x32_bf16(av, bv1, ac1, 0, 0, 0);
        ac2 = __builtin_amdgcn_mfma_f32_16x16x32_bf16(av, bv2, ac2, 0, 0, 0);
    }
    const int orow = (lane >> 4) * 4;
    const int sc = s0 + fr;
    const float bc = bsg[sc], bd = bsg[512 + sc], bg = bsg[1024 + sc];
    #pragma unroll
    for (int j = 0; j < 4; ++j) {
        int r = r0 + orow + j;
        float craw = ac0[j] + bc;
        float dw   = ac1[j] + bd;
        float graw = ac2[j] + bg;
        float gv = 1.0f / (1.0f + expf(-graw));
        float xcv = xc[(size_t)r * IDIM + sc];
        Cw[(size_t)r * IDIM + sc] = gv * craw;
        u[(size_t)r * IDIM + sc]  = xcv * dw * dw;
    }
}

// ---------------------------------------------------------------------------
// k4_fused: cooperative scan. 512 blocks x 256 thr = 2048 waves.
// Wave = (b, c, sh, ig): lane covers 4 s (within s-half sh), 8 i-values.
// Phase1: chunk-local scan -> carry to C_loc[b][c][i][s].
// Phase2: in-place chunk prefix combine (thread per (b,i,s4)).
// Phase3: seeded scan + contraction; per-l reduce via stageA(8,16,32)+
//         select+stageB(1,2,4) = 27 shfl per 8 outputs; write half-partials.
// Phase4: add halves + u*D, convert to bf16 y.
// ---------------------------------------------------------------------------
__global__ __launch_bounds__(256, 2) void k4_fused(const float* __restrict__ u,
                                                   const float* __restrict__ Cw,
                                                   const float* __restrict__ A,
                                                   const float* __restrict__ D,
                                                   float* __restrict__ C_loc,
                                                   float* __restrict__ patl,
                                                   unsigned short* __restrict__ ybb) {
    cooperative_groups::grid_group grid = cooperative_groups::this_grid();
    const int tid = blockIdx.x * 256 + threadIdx.x;   // 0..131071
    const int wave = tid >> 6;                        // 0..2047
    const int lane = threadIdx.x & 63;
    const int ig = wave & 63;
    const int sh = (wave >> 6) & 1;
    const int c  = (wave >> 7) & (NC - 1);
    const int b  = wave >> 10;
    const int i8 = ig * 8;
    const int s4 = sh * 256 + lane * 4;               // lane's s base

    float a[4][8], h[4][8];
    #pragma unroll
    for (int k = 0; k < 4; ++k) {
        float4 a0 = *(const float4*)&A[(size_t)(s4 + k) * IDIM + i8];
        float4 a1 = *(const float4*)&A[(size_t)(s4 + k) * IDIM + i8 + 4];
        a[k][0] = a0.x; a[k][1] = a0.y; a[k][2] = a0.z; a[k][3] = a0.w;
        a[k][4] = a1.x; a[k][5] = a1.y; a[k][6] = a1.z; a[k][7] = a1.w;
        #pragma unroll
        for (int ii = 0; ii < 8; ++ii) h[k][ii] = 0.f;
    }

    // ---- Phase 1: local scan, write carry
    {
        const float* ub = u + ((size_t)b * LSEQ + c * TCH) * IDIM;
        for (int l = 0; l < TCH; ++l) {
            float4 u4 = *(const float4*)(ub + l * IDIM + s4);
            float uu[4] = {u4.x, u4.y, u4.z, u4.w};
            #pragma unroll
            for (int ii = 0; ii < 8; ++ii)
                #pragma unroll
                for (int k = 0; k < 4; ++k)
                    h[k][ii] = h[k][ii] * a[k][ii] + uu[k];
        }
        #pragma unroll
        for (int ii = 0; ii < 8; ++ii) {
            float4 v;
            v.x = h[0][ii]; v.y = h[1][ii]; v.z = h[2][ii]; v.w = h[3][ii];
            *(float4*)&C_loc[(((size_t)b * NC + c) * IDIM + i8 + ii) * IDIM + s4] = v;
        }
    }
    grid.sync();

    // ---- Phase 2: in-place prefix combine over chunks
    {
        const int ss4 = (tid & 127) * 4;
        const int i  = (tid >> 7) & 511;
        const int bb = tid >> 16;
        float da[4], h4[4] = {0.f, 0.f, 0.f, 0.f};
        #pragma unroll
        for (int j = 0; j < 4; ++j) {
            float aa = A[(size_t)(ss4 + j) * IDIM + i];
            aa = aa * aa; aa = aa * aa; aa = aa * aa;
            aa = aa * aa; aa = aa * aa;               // ^32 == TCH
            da[j] = aa;
        }
        for (int cc = 0; cc < NC; ++cc) {
            size_t base = (((size_t)bb * NC + cc) * IDIM + i) * IDIM + ss4;
            float4 cl = *(const float4*)&C_loc[base];
            float4 hv;
            hv.x = h4[0]; hv.y = h4[1]; hv.z = h4[2]; hv.w = h4[3];
            *(float4*)&C_loc[base] = hv;              // state entering chunk cc
            h4[0] = h4[0] * da[0] + cl.x;
            h4[1] = h4[1] * da[1] + cl.y;
            h4[2] = h4[2] * da[2] + cl.z;
            h4[3] = h4[3] * da[3] + cl.w;
        }
    }
    grid.sync();

    // ---- Phase 3: seeded scan + contraction, write per-half partials
    {
        #pragma unroll
        for (int ii = 0; ii < 8; ++ii) {
            float4 hv = *(const float4*)&C_loc[(((size_t)b * NC + c) * IDIM + i8 + ii) * IDIM + s4];
            h[0][ii] = hv.x; h[1][ii] = hv.y; h[2][ii] = hv.z; h[3][ii] = hv.w;
        }
        const float* ub = u + (size_t)b * LSEQ * IDIM;
        const float* cb = Cw + (size_t)b * LSEQ * IDIM;
        float* prow = patl + ((size_t)(b * 2 + sh) * LSEQ) * IDIM;
        const bool w8 = ((lane & 7) == 0);
        const int iiw = lane >> 3;
        for (int l = c * TCH; l < c * TCH + TCH; ++l) {
            float4 u4 = *(const float4*)(ub + l * IDIM + s4);
            float4 c4 = *(const float4*)(cb + l * IDIM + s4);
            float uu[4] = {u4.x, u4.y, u4.z, u4.w};
            float cc[4] = {c4.x, c4.y, c4.z, c4.w};
            float p[8];
            #pragma unroll
            for (int ii = 0; ii < 8; ++ii) {
                float acc = 0.f;
                #pragma unroll
                for (int k = 0; k < 4; ++k) {
                    h[k][ii] = h[k][ii] * a[k][ii] + uu[k];
                    acc += cc[k] * h[k][ii];
                }
                p[ii] = acc;
            }
            // stage A: sum out lane bits 3,4,5 (all 8 values)
            #pragma unroll
            for (int ii = 0; ii < 8; ++ii) p[ii] += __shfl_xor(p[ii], 8, 64);
            #pragma unroll
            for (int ii = 0; ii < 8; ++ii) p[ii] += __shfl_xor(p[ii], 16, 64);
            #pragma unroll
            for (int ii = 0; ii < 8; ++ii) p[ii] += __shfl_xor(p[ii], 32, 64);
            // select: 8-lane block j handles ii=j
            float q = (lane & 32) ? ((lane & 16) ? ((lane & 8) ? p[7] : p[6])
                                                 : ((lane & 8) ? p[5] : p[4]))
                                  : ((lane & 16) ? ((lane & 8) ? p[3] : p[2])
                                                 : ((lane & 8) ? p[1] : p[0]));
            // stage B: sum out lane bits 0,1,2
            q += __shfl_xor(q, 1, 64);
            q += __shfl_xor(q, 2, 64);
            q += __shfl_xor(q, 4, 64);
            if (w8) prow[(size_t)l * IDIM + i8 + iiw] = q;
        }
    }
    grid.sync();

    // ---- Phase 4: add halves + u*D, cvt bf16
    {
        const int idx = tid * 2;                      // covers 2*256*512
        const int i = idx & 511;
        const int l = (idx >> 9) & 255;
        const int bb = idx >> 17;
        float2 p0 = *(const float2*)&patl[(((size_t)bb * 2 + 0) * LSEQ + l) * IDIM + i];
        float2 p1 = *(const float2*)&patl[(((size_t)bb * 2 + 1) * LSEQ + l) * IDIM + i];
        float2 uv = *(const float2*)&u[((size_t)bb * LSEQ + l) * IDIM + i];
        float2 dv = *(const float2*)&D[i];
        size_t yo = ((size_t)bb * LSEQ + l) * IDIM + i;
        ybb[yo]     = f2b(p0.x + p1.x + uv.x * dv.x);
        ybb[yo + 1] = f2b(p0.y + p1.y + uv.y * dv.y);
    }
}

// ---------------------------------------------------------------------------
// k5a: outlin = y @ W_out^T (512x256, K=512). Wave per 16x16 tile.
// ---------------------------------------------------------------------------
__global__ __launch_bounds__(256) void k5a_mfma(const unsigned short* __restrict__ ybb,
                                                const unsigned short* __restrict__ W_outb,
                                                float* __restrict__ outlin) {
    const int t = threadIdx.x;
    const int w = blockIdx.x * 4 + (t >> 6);   // 0..511
    const int lane = t & 63;
    const int mt = w >> 4, nt = w & 15;
    const int r0 = mt * 16, h0 = nt * 16;
    const int fr = lane & 15, fk = (lane >> 4) * 8;
    const unsigned short* ap = ybb + (size_t)(r0 + fr) * IDIM + fk;
    const unsigned short* bp = W_outb + (size_t)(h0 + fr) * IDIM + fk;
    f32x4 acc = {0.f, 0.f, 0.f, 0.f};
    #pragma unroll
    for (int k0 = 0; k0 < IDIM; k0 += 32) {
        bf16x8 av = *(const bf16x8*)(ap + k0);
        bf16x8 bv = *(const bf16x8*)(bp + k0);
        acc = __builtin_amdgcn_mfma_f32_16x16x32_bf16(av, bv, acc, 0, 0, 0);
    }
    const int orow = (lane >> 4) * 4;
    const int hc = h0 + fr;
    #pragma unroll
    for (int j = 0; j < 4; ++j)
        outlin[(size_t)(r0 + orow + j) * HDIM + hc] = acc[j];
}

// ---------------------------------------------------------------------------
// K5b: LayerNorm over H=256 + z scale + residual. One block per row.
// ---------------------------------------------------------------------------
__global__ __launch_bounds__(256) void k5b_ln(const float* __restrict__ outlin,
                                              const float* __restrict__ x,
                                              const float* __restrict__ z,
                                              const float* __restrict__ ln_g,
                                              const float* __restrict__ ln_b,
                                              float* __restrict__ out) {
    const int r = blockIdx.x;
    const int t = threadIdx.x;
    float v = outlin[(size_t)r * HDIM + t];
    float s1 = v, s2 = v * v;
    #pragma unroll
    for (int off = 1; off < 64; off <<= 1) {
        s1 += __shfl_xor(s1, off, 64);
        s2 += __shfl_xor(s2, off, 64);
    }
    __shared__ float r1[4], r2[4];
    const int w = t >> 6, lane = t & 63;
    if (lane == 0) { r1[w] = s1; r2[w] = s2; }
    __syncthreads();
    float t1 = r1[0] + r1[1] + r1[2] + r1[3];
    float t2 = r2[0] + r2[1] + r2[2] + r2[3];
    float mu = t1 * (1.0f / 256.0f);
    float var = t2 * (1.0f / 256.0f) - mu * mu;
    float inv = rsqrtf(var + 1e-5f);
    float o = (v - mu) * inv * ln_g[t] + ln_b[t];
    out[(size_t)r * HDIM + t] = o * z[0] + x[(size_t)r * HDIM + t];
}

// ---------------------------------------------------------------------------
extern "C" void kernel_launch(void* const* d_in, const int* in_sizes, int n_in,
                              void* d_out, int out_size, void* d_ws, size_t ws_size,
                              hipStream_t stream) {
    const float* x      = (const float*)d_in[0];
    const float* W_in   = (const float*)d_in[1];
    const float* conv_w = (const float*)d_in[2];
    const float* conv_b = (const float*)d_in[3];
    const float* W_ssm  = (const float*)d_in[4];
    const float* b_ssm  = (const float*)d_in[5];
    const float* W_gate = (const float*)d_in[6];
    const float* b_gate = (const float*)d_in[7];
    const float* A      = (const float*)d_in[8];
    const float* D      = (const float*)d_in[9];
    const float* W_out  = (const float*)d_in[10];
    const float* z      = (const float*)d_in[11];
    const float* ln_g   = (const float*)d_in[12];
    const float* ln_b   = (const float*)d_in[13];
    float* out = (float*)d_out;

    float* ws = (float*)d_ws;
    float*          xq_g   = ws;                               // 262144 f32 (dead after k3f)
    float*          xc     = ws + 262144;                      // 262144 f32 (dead after k3f)
    float*          patl   = ws;                               // 524288 f32, ALIASES xq_g+xc
    float*          Cw     = ws + 524288;                      // 262144 f32
    float*          u      = ws + 786432;                      // 262144 f32
    float*          outlin = ws + 1048576;                     // 131072 f32
    float*          bsg    = ws + 1179648;                     // 2048 f32 (1536 used)
    unsigned short* xcb    = (unsigned short*)(ws + 1181696);  // 262144 bf16
    unsigned short* xkb    = (unsigned short*)(ws + 1312768);  // 262144 bf16
    unsigned short* Wsgb   = (unsigned short*)(ws + 1443840);  // 786432 bf16
    unsigned short* W_outb = (unsigned short*)(ws + 1837056);  // 131072 bf16
    unsigned short* ybb    = (unsigned short*)(ws + 1902592);  // 262144 bf16
    // AREA: {xb, Wb, cwb} dead after kxc; reused for C_loc (NC=8, in-place)
    float*          area   = ws + 2033664;                     // 4194304 f32
    unsigned short* xb     = (unsigned short*)area;            // 131072 bf16
    unsigned short* Wb     = (unsigned short*)(area + 65536);  // 262144 bf16
    unsigned short* cwb    = (unsigned short*)(area + 196608); // 786432 bf16
    float*          C_loc  = area;                             // 2*8*512*512 = 4194304 f32

    kcvt     <<<512, 256, 0, stream>>>(x, W_in, conv_w, W_ssm, W_gate, b_ssm,
                                       b_gate, W_out, xb, Wb, cwb, Wsgb, bsg, W_outb);
    k1_mfma  <<<512, 256, 0, stream>>>(xb, Wb, xq_g, xkb);
    kxc_mfma <<<256, 256, 0, stream>>>(xkb, cwb, xq_g, conv_b, xc, xcb);
    k3f_mfma <<<256, 256, 0, stream>>>(xcb, Wsgb, bsg, xc, Cw, u);

    {
        const float* u_c = u;  const float* Cw_c = Cw;
        const float* A_c = A;  const float* D_c = D;
        float* C_loc_c = C_loc; float* patl_c = patl;
        unsigned short* ybb_c = ybb;
        void* args[] = {(void*)&u_c, (void*)&Cw_c, (void*)&A_c, (void*)&D_c,
                        (void*)&C_loc_c, (void*)&patl_c, (void*)&ybb_c};
        hipLaunchCooperativeKernel((void*)k4_fused, dim3(512), dim3(256),
                                   args, 0, stream);
    }

    k5a_mfma <<<128, 256, 0, stream>>>(ybb, W_outb, outlin);
    k5b_ln   <<<512, 256, 0, stream>>>(outlin, x, z, ln_g, ln_b, out);
}

// Round 10
// 102.434 us; speedup vs baseline: 2.7813x; 2.7813x over previous
//
#include <hip/hip_runtime.h>
#include <math.h>

// Problem dims
#define NB    2
#define LSEQ  256
#define HDIM  256
#define IDIM  512
#define NROW  512      // NB*LSEQ
#define NC    8        // scan chunks
#define TCH   32       // chunk length (NC*TCH == LSEQ)

typedef __attribute__((ext_vector_type(8))) short bf16x8;
typedef __attribute__((ext_vector_type(4))) float f32x4;

__device__ inline unsigned short f2b(float f) {
    unsigned u = __float_as_uint(f);
    return (unsigned short)((u + 0x7FFFu + ((u >> 16) & 1u)) >> 16);
}

// ---------------------------------------------------------------------------
// kcvt: convert x, W_in, conv_w (3 transposed planes), fused Wsg, bsg, W_out
// to bf16 staging buffers. Memory-bound, grid-stride.
// ---------------------------------------------------------------------------
__global__ __launch_bounds__(256) void kcvt(const float* __restrict__ x,
                                            const float* __restrict__ W_in,
                                            const float* __restrict__ conv_w,
                                            const float* __restrict__ W_ssm,
                                            const float* __restrict__ W_gate,
                                            const float* __restrict__ b_ssm,
                                            const float* __restrict__ b_gate,
                                            const float* __restrict__ W_out,
                                            unsigned short* __restrict__ xb,
                                            unsigned short* __restrict__ Wb,
                                            unsigned short* __restrict__ cwb,
                                            unsigned short* __restrict__ Wsgb,
                                            float* __restrict__ bsg,
                                            unsigned short* __restrict__ W_outb) {
    const int stride = gridDim.x * 256;
    const int t0 = blockIdx.x * 256 + threadIdx.x;
    for (int i = t0; i < 131072; i += stride) xb[i] = f2b(x[i]);
    for (int i = t0; i < 262144; i += stride) Wb[i] = f2b(W_in[i]);
    // cwb[k][o][i] = conv_w[o][i][k]; thread handles one (o,i), 3 planes
    for (int d = t0; d < 262144; d += stride) {
        const float* s = conv_w + (size_t)d * 3;
        cwb[d]          = f2b(s[0]);
        cwb[262144 + d] = f2b(s[1]);
        cwb[524288 + d] = f2b(s[2]);
    }
    // Wsgb rows: 0..1023 = W_ssm[512..1535]; 1024..1535 = W_gate[512..1023]
    for (int d = t0; d < 786432; d += stride) {
        int j = d >> 9, i = d & 511;
        float v = (j < 1024) ? W_ssm[(size_t)(512 + j) * 512 + i]
                             : W_gate[(size_t)(j - 512) * 512 + i];
        Wsgb[d] = f2b(v);
    }
    for (int j = t0; j < 1536; j += stride)
        bsg[j] = (j < 1024) ? b_ssm[512 + j] : b_gate[j - 512];
    for (int i = t0; i < 131072; i += stride) W_outb[i] = f2b(W_out[i]);
}

// ---------------------------------------------------------------------------
// k1: xp = x @ W_in^T (512x1024, K=256). Wave per 16x16 tile, no LDS.
// ---------------------------------------------------------------------------
__global__ __launch_bounds__(256) void k1_mfma(const unsigned short* __restrict__ xb,
                                               const unsigned short* __restrict__ Wb,
                                               float* __restrict__ xq_g,
                                               unsigned short* __restrict__ xkb) {
    const int t = threadIdx.x;
    const int w = blockIdx.x * 4 + (t >> 6);   // 0..2047
    const int lane = t & 63;
    const int mt = w >> 6, nt = w & 63;
    const int r0 = mt * 16, n0 = nt * 16;
    const int fr = lane & 15, fk = (lane >> 4) * 8;
    const unsigned short* ap = xb + (size_t)(r0 + fr) * HDIM + fk;
    const unsigned short* bp = Wb + (size_t)(n0 + fr) * HDIM + fk;
    f32x4 acc = {0.f, 0.f, 0.f, 0.f};
    #pragma unroll
    for (int k0 = 0; k0 < HDIM; k0 += 32) {
        bf16x8 av = *(const bf16x8*)(ap + k0);
        bf16x8 bv = *(const bf16x8*)(bp + k0);
        acc = __builtin_amdgcn_mfma_f32_16x16x32_bf16(av, bv, acc, 0, 0, 0);
    }
    const int orow = (lane >> 4) * 4;
    const int oc = n0 + fr;
    if (oc < IDIM) {
        #pragma unroll
        for (int j = 0; j < 4; ++j) {
            float v = acc[j];
            xq_g[(size_t)(r0 + orow + j) * IDIM + oc] =
                0.5f * v * (1.0f + erff(v * 0.70710678118654752f));
        }
    } else {
        #pragma unroll
        for (int j = 0; j < 4; ++j)
            xkb[(size_t)(r0 + orow + j) * IDIM + (oc - IDIM)] = f2b(acc[j]);
    }
}

// ---------------------------------------------------------------------------
// kxc: xc[r,o] = gelu_q[r,o] + conv_b[o] + sum_k xk[r+k-1,:]·cwb[k][o,:]
// ---------------------------------------------------------------------------
__global__ __launch_bounds__(256) void kxc_mfma(const unsigned short* __restrict__ xkb,
                                                const unsigned short* __restrict__ cwb,
                                                const float* __restrict__ xq_g,
                                                const float* __restrict__ conv_b,
                                                float* __restrict__ xc,
                                                unsigned short* __restrict__ xcb) {
    const int t = threadIdx.x;
    const int w = blockIdx.x * 4 + (t >> 6);   // 0..1023
    const int lane = t & 63;
    const int mt = w >> 5, nt = w & 31;
    const int r0 = mt * 16, o0 = nt * 16;
    const int fr = lane & 15, fk = (lane >> 4) * 8;
    const int g = r0 + fr;
    const int lo = r0 & ~255, hi = lo + 256;
    const bool okm = (g - 1 >= lo), okp = (g + 1 < hi);
    const unsigned short* am = xkb + (size_t)(g - 1) * IDIM + fk;
    const unsigned short* a0 = xkb + (size_t)g * IDIM + fk;
    const unsigned short* ap = xkb + (size_t)(g + 1) * IDIM + fk;
    const unsigned short* b0 = cwb + (size_t)(o0 + fr) * IDIM + fk;
    const unsigned short* b1 = b0 + 262144;
    const unsigned short* b2 = b0 + 524288;
    const bf16x8 zz = {0, 0, 0, 0, 0, 0, 0, 0};
    f32x4 acc = {0.f, 0.f, 0.f, 0.f};
    #pragma unroll
    for (int k0 = 0; k0 < IDIM; k0 += 32) {
        bf16x8 avm = okm ? *(const bf16x8*)(am + k0) : zz;
        bf16x8 av0 = *(const bf16x8*)(a0 + k0);
        bf16x8 avp = okp ? *(const bf16x8*)(ap + k0) : zz;
        bf16x8 bv0 = *(const bf16x8*)(b0 + k0);
        bf16x8 bv1 = *(const bf16x8*)(b1 + k0);
        bf16x8 bv2 = *(const bf16x8*)(b2 + k0);
        acc = __builtin_amdgcn_mfma_f32_16x16x32_bf16(avm, bv0, acc, 0, 0, 0);
        acc = __builtin_amdgcn_mfma_f32_16x16x32_bf16(av0, bv1, acc, 0, 0, 0);
        acc = __builtin_amdgcn_mfma_f32_16x16x32_bf16(avp, bv2, acc, 0, 0, 0);
    }
    const int orow = (lane >> 4) * 4;
    const int oc = o0 + fr;
    const float cb = conv_b[oc];
    #pragma unroll
    for (int j = 0; j < 4; ++j) {
        int r = r0 + orow + j;
        float v = acc[j] + xq_g[(size_t)r * IDIM + oc] + cb;
        xc[(size_t)r * IDIM + oc] = v;
        xcb[(size_t)r * IDIM + oc] = f2b(v);
    }
}

// ---------------------------------------------------------------------------
// k3f: fused ssm/gate GEMM + elementwise. Wave computes tiles (r0, s0),
// (r0, 512+s0), (r0, 1024+s0) of E sharing the A fragment, then:
//   Cw[r,s] = sigmoid(graw)*craw;  u[r,s] = xc[r,s]*dw*dw
// ---------------------------------------------------------------------------
__global__ __launch_bounds__(256) void k3f_mfma(const unsigned short* __restrict__ xcb,
                                                const unsigned short* __restrict__ Wsgb,
                                                const float* __restrict__ bsg,
                                                const float* __restrict__ xc,
                                                float* __restrict__ Cw,
                                                float* __restrict__ u) {
    const int t = threadIdx.x;
    const int w = blockIdx.x * 4 + (t >> 6);   // 0..1023
    const int lane = t & 63;
    const int mt = w >> 5, nt = w & 31;
    const int r0 = mt * 16, s0 = nt * 16;
    const int fr = lane & 15, fk = (lane >> 4) * 8;
    const unsigned short* ap = xcb + (size_t)(r0 + fr) * IDIM + fk;
    const unsigned short* b0 = Wsgb + (size_t)(s0 + fr) * IDIM + fk;
    const unsigned short* b1 = Wsgb + (size_t)(512 + s0 + fr) * IDIM + fk;
    const unsigned short* b2 = Wsgb + (size_t)(1024 + s0 + fr) * IDIM + fk;
    f32x4 ac0 = {0.f, 0.f, 0.f, 0.f};
    f32x4 ac1 = {0.f, 0.f, 0.f, 0.f};
    f32x4 ac2 = {0.f, 0.f, 0.f, 0.f};
    #pragma unroll
    for (int k0 = 0; k0 < IDIM; k0 += 32) {
        bf16x8 av  = *(const bf16x8*)(ap + k0);
        bf16x8 bv0 = *(const bf16x8*)(b0 + k0);
        bf16x8 bv1 = *(const bf16x8*)(b1 + k0);
        bf16x8 bv2 = *(const bf16x8*)(b2 + k0);
        ac0 = __builtin_amdgcn_mfma_f32_16x16x32_bf16(av, bv0, ac0, 0, 0, 0);
        ac1 = __builtin_amdgcn_mfma_f32_16x16x32_bf16(av, bv1, ac1, 0, 0, 0);
        ac2 = __builtin_amdgcn_mfma_f32_16x16x32_bf16(av, bv2, ac2, 0, 0, 0);
    }
    const int orow = (lane >> 4) * 4;
    const int sc = s0 + fr;
    const float bc = bsg[sc], bd = bsg[512 + sc], bg = bsg[1024 + sc];
    #pragma unroll
    for (int j = 0; j < 4; ++j) {
        int r = r0 + orow + j;
        float craw = ac0[j] + bc;
        float dw   = ac1[j] + bd;
        float graw = ac2[j] + bg;
        float gv = 1.0f / (1.0f + expf(-graw));
        float xcv = xc[(size_t)r * IDIM + sc];
        Cw[(size_t)r * IDIM + sc] = gv * craw;
        u[(size_t)r * IDIM + sc]  = xcv * dw * dw;
    }
}

// ---------------------------------------------------------------------------
// K4a: chunk-local scan, s-half split. Wave = (b,c,sh,ig): lane owns 4 s
// (in half sh) x 8 i. 2048 waves -> 2 waves/SIMD. Writes carry quarter.
// ---------------------------------------------------------------------------
__global__ __launch_bounds__(256) void k4a_pass1(const float* __restrict__ u,
                                                 const float* __restrict__ A,
                                                 float* __restrict__ C_loc) {
    const int wave = (blockIdx.x * 256 + threadIdx.x) >> 6;  // 0..2047
    const int lane = threadIdx.x & 63;
    const int ig = wave & 63;
    const int sh = (wave >> 6) & 1;
    const int c  = (wave >> 7) & (NC - 1);
    const int b  = wave >> 10;
    const int i8 = ig * 8;
    const int s4 = sh * 256 + lane * 4;
    float a[4][8], h[4][8];
    #pragma unroll
    for (int k = 0; k < 4; ++k) {
        float4 a0 = *(const float4*)&A[(size_t)(s4 + k) * IDIM + i8];
        float4 a1 = *(const float4*)&A[(size_t)(s4 + k) * IDIM + i8 + 4];
        a[k][0] = a0.x; a[k][1] = a0.y; a[k][2] = a0.z; a[k][3] = a0.w;
        a[k][4] = a1.x; a[k][5] = a1.y; a[k][6] = a1.z; a[k][7] = a1.w;
        #pragma unroll
        for (int ii = 0; ii < 8; ++ii) h[k][ii] = 0.f;
    }
    const float* ub = u + ((size_t)b * LSEQ + c * TCH) * IDIM;
    for (int l = 0; l < TCH; ++l) {
        float4 u4 = *(const float4*)(ub + l * IDIM + s4);
        float uu[4] = {u4.x, u4.y, u4.z, u4.w};
        #pragma unroll
        for (int ii = 0; ii < 8; ++ii)
            #pragma unroll
            for (int k = 0; k < 4; ++k)
                h[k][ii] = h[k][ii] * a[k][ii] + uu[k];
    }
    #pragma unroll
    for (int ii = 0; ii < 8; ++ii) {
        float4 v;
        v.x = h[0][ii]; v.y = h[1][ii]; v.z = h[2][ii]; v.w = h[3][ii];
        *(float4*)&C_loc[(((size_t)b * NC + c) * IDIM + i8 + ii) * IDIM + s4] = v;
    }
}

// ---------------------------------------------------------------------------
// K4b: sequential combine IN-PLACE: C_loc[b][c] is replaced by the state
// ENTERING chunk c. Thread per (b,i,s4).
// ---------------------------------------------------------------------------
__global__ __launch_bounds__(256) void k4b_combine(const float* __restrict__ A,
                                                   float* __restrict__ C_loc) {
    int idx = blockIdx.x * 256 + threadIdx.x;   // < 2*512*128
    int s4 = (idx & 127) * 4;
    int i  = (idx >> 7) & 511;
    int b  = idx >> 16;
    float da[4], h4[4] = {0.0f, 0.0f, 0.0f, 0.0f};
    #pragma unroll
    for (int j = 0; j < 4; ++j) {
        float aa = A[(size_t)(s4 + j) * IDIM + i];
        aa = aa * aa; aa = aa * aa; aa = aa * aa;
        aa = aa * aa; aa = aa * aa;                 // ^32 == TCH
        da[j] = aa;
    }
    for (int c = 0; c < NC; ++c) {
        size_t base = (((size_t)b * NC + c) * IDIM + i) * IDIM + s4;
        float4 cl = *(const float4*)&C_loc[base];   // carry of chunk c
        float4 hv;
        hv.x = h4[0]; hv.y = h4[1]; hv.z = h4[2]; hv.w = h4[3];
        *(float4*)&C_loc[base] = hv;                // state entering chunk c
        h4[0] = h4[0] * da[0] + cl.x;
        h4[1] = h4[1] * da[1] + cl.y;
        h4[2] = h4[2] * da[2] + cl.z;
        h4[3] = h4[3] * da[3] + cl.w;
    }
}

// ---------------------------------------------------------------------------
// K4c: seeded scan + contraction, s-half split; 27-shfl reduction per l
// (stageA xor 8/16/32 on 8 vals -> lane-bit select -> stageB xor 1/2/4).
// Writes per-half partial rows. 2048 waves.
// ---------------------------------------------------------------------------
__global__ __launch_bounds__(256) void k4c_pass2(const float* __restrict__ u,
                                                 const float* __restrict__ Cw,
                                                 const float* __restrict__ A,
                                                 const float* __restrict__ H,
                                                 float* __restrict__ patl) {
    const int wave = (blockIdx.x * 256 + threadIdx.x) >> 6;  // 0..2047
    const int lane = threadIdx.x & 63;
    const int ig = wave & 63;
    const int sh = (wave >> 6) & 1;
    const int c  = (wave >> 7) & (NC - 1);
    const int b  = wave >> 10;
    const int i8 = ig * 8;
    const int s4 = sh * 256 + lane * 4;
    float a[4][8], h[4][8];
    #pragma unroll
    for (int k = 0; k < 4; ++k) {
        float4 a0 = *(const float4*)&A[(size_t)(s4 + k) * IDIM + i8];
        float4 a1 = *(const float4*)&A[(size_t)(s4 + k) * IDIM + i8 + 4];
        a[k][0] = a0.x; a[k][1] = a0.y; a[k][2] = a0.z; a[k][3] = a0.w;
        a[k][4] = a1.x; a[k][5] = a1.y; a[k][6] = a1.z; a[k][7] = a1.w;
    }
    #pragma unroll
    for (int ii = 0; ii < 8; ++ii) {
        float4 hv = *(const float4*)&H[(((size_t)b * NC + c) * IDIM + i8 + ii) * IDIM + s4];
        h[0][ii] = hv.x; h[1][ii] = hv.y; h[2][ii] = hv.z; h[3][ii] = hv.w;
    }
    const float* ub = u + (size_t)b * LSEQ * IDIM;
    const float* cb = Cw + (size_t)b * LSEQ * IDIM;
    float* prow = patl + ((size_t)(b * 2 + sh) * LSEQ) * IDIM;
    const bool w8 = ((lane & 7) == 0);
    const int iiw = lane >> 3;
    for (int l = c * TCH; l < c * TCH + TCH; ++l) {
        float4 u4 = *(const float4*)(ub + l * IDIM + s4);
        float4 c4 = *(const float4*)(cb + l * IDIM + s4);
        float uu[4] = {u4.x, u4.y, u4.z, u4.w};
        float cc[4] = {c4.x, c4.y, c4.z, c4.w};
        float p[8];
        #pragma unroll
        for (int ii = 0; ii < 8; ++ii) {
            float acc = 0.f;
            #pragma unroll
            for (int k = 0; k < 4; ++k) {
                h[k][ii] = h[k][ii] * a[k][ii] + uu[k];
                acc += cc[k] * h[k][ii];
            }
            p[ii] = acc;
        }
        #pragma unroll
        for (int ii = 0; ii < 8; ++ii) p[ii] += __shfl_xor(p[ii], 8, 64);
        #pragma unroll
        for (int ii = 0; ii < 8; ++ii) p[ii] += __shfl_xor(p[ii], 16, 64);
        #pragma unroll
        for (int ii = 0; ii < 8; ++ii) p[ii] += __shfl_xor(p[ii], 32, 64);
        float q = (lane & 32) ? ((lane & 16) ? ((lane & 8) ? p[7] : p[6])
                                             : ((lane & 8) ? p[5] : p[4]))
                              : ((lane & 16) ? ((lane & 8) ? p[3] : p[2])
                                             : ((lane & 8) ? p[1] : p[0]));
        q += __shfl_xor(q, 1, 64);
        q += __shfl_xor(q, 2, 64);
        q += __shfl_xor(q, 4, 64);
        if (w8) prow[(size_t)l * IDIM + i8 + iiw] = q;
    }
}

// ---------------------------------------------------------------------------
// K4d: y = half0 + half1 + u*D, convert bf16. 512 blocks x 256 thr x 2 elems.
// ---------------------------------------------------------------------------
__global__ __launch_bounds__(256) void k4d_add(const float* __restrict__ patl,
                                               const float* __restrict__ u,
                                               const float* __restrict__ D,
                                               unsigned short* __restrict__ ybb) {
    const int idx = (blockIdx.x * 256 + threadIdx.x) * 2;   // < 2*256*512
    const int i = idx & 511;
    const int l = (idx >> 9) & 255;
    const int bb = idx >> 17;
    float2 p0 = *(const float2*)&patl[(((size_t)bb * 2 + 0) * LSEQ + l) * IDIM + i];
    float2 p1 = *(const float2*)&patl[(((size_t)bb * 2 + 1) * LSEQ + l) * IDIM + i];
    float2 uv = *(const float2*)&u[((size_t)bb * LSEQ + l) * IDIM + i];
    float2 dv = *(const float2*)&D[i];
    size_t yo = ((size_t)bb * LSEQ + l) * IDIM + i;
    ybb[yo]     = f2b(p0.x + p1.x + uv.x * dv.x);
    ybb[yo + 1] = f2b(p0.y + p1.y + uv.y * dv.y);
}

// ---------------------------------------------------------------------------
// k5a: outlin = y @ W_out^T (512x256, K=512). Wave per 16x16 tile.
// ---------------------------------------------------------------------------
__global__ __launch_bounds__(256) void k5a_mfma(const unsigned short* __restrict__ ybb,
                                                const unsigned short* __restrict__ W_outb,
                                                float* __restrict__ outlin) {
    const int t = threadIdx.x;
    const int w = blockIdx.x * 4 + (t >> 6);   // 0..511
    const int lane = t & 63;
    const int mt = w >> 4, nt = w & 15;
    const int r0 = mt * 16, h0 = nt * 16;
    const int fr = lane & 15, fk = (lane >> 4) * 8;
    const unsigned short* ap = ybb + (size_t)(r0 + fr) * IDIM + fk;
    const unsigned short* bp = W_outb + (size_t)(h0 + fr) * IDIM + fk;
    f32x4 acc = {0.f, 0.f, 0.f, 0.f};
    #pragma unroll
    for (int k0 = 0; k0 < IDIM; k0 += 32) {
        bf16x8 av = *(const bf16x8*)(ap + k0);
        bf16x8 bv = *(const bf16x8*)(bp + k0);
        acc = __builtin_amdgcn_mfma_f32_16x16x32_bf16(av, bv, acc, 0, 0, 0);
    }
    const int orow = (lane >> 4) * 4;
    const int hc = h0 + fr;
    #pragma unroll
    for (int j = 0; j < 4; ++j)
        outlin[(size_t)(r0 + orow + j) * HDIM + hc] = acc[j];
}

// ---------------------------------------------------------------------------
// K5b: LayerNorm over H=256 + z scale + residual. One block per row.
// ---------------------------------------------------------------------------
__global__ __launch_bounds__(256) void k5b_ln(const float* __restrict__ outlin,
                                              const float* __restrict__ x,
                                              const float* __restrict__ z,
                                              const float* __restrict__ ln_g,
                                              const float* __restrict__ ln_b,
                                              float* __restrict__ out) {
    const int r = blockIdx.x;
    const int t = threadIdx.x;
    float v = outlin[(size_t)r * HDIM + t];
    float s1 = v, s2 = v * v;
    #pragma unroll
    for (int off = 1; off < 64; off <<= 1) {
        s1 += __shfl_xor(s1, off, 64);
        s2 += __shfl_xor(s2, off, 64);
    }
    __shared__ float r1[4], r2[4];
    const int w = t >> 6, lane = t & 63;
    if (lane == 0) { r1[w] = s1; r2[w] = s2; }
    __syncthreads();
    float t1 = r1[0] + r1[1] + r1[2] + r1[3];
    float t2 = r2[0] + r2[1] + r2[2] + r2[3];
    float mu = t1 * (1.0f / 256.0f);
    float var = t2 * (1.0f / 256.0f) - mu * mu;
    float inv = rsqrtf(var + 1e-5f);
    float o = (v - mu) * inv * ln_g[t] + ln_b[t];
    out[(size_t)r * HDIM + t] = o * z[0] + x[(size_t)r * HDIM + t];
}

// ---------------------------------------------------------------------------
extern "C" void kernel_launch(void* const* d_in, const int* in_sizes, int n_in,
                              void* d_out, int out_size, void* d_ws, size_t ws_size,
                              hipStream_t stream) {
    const float* x      = (const float*)d_in[0];
    const float* W_in   = (const float*)d_in[1];
    const float* conv_w = (const float*)d_in[2];
    const float* conv_b = (const float*)d_in[3];
    const float* W_ssm  = (const float*)d_in[4];
    const float* b_ssm  = (const float*)d_in[5];
    const float* W_gate = (const float*)d_in[6];
    const float* b_gate = (const float*)d_in[7];
    const float* A      = (const float*)d_in[8];
    const float* D      = (const float*)d_in[9];
    const float* W_out  = (const float*)d_in[10];
    const float* z      = (const float*)d_in[11];
    const float* ln_g   = (const float*)d_in[12];
    const float* ln_b   = (const float*)d_in[13];
    float* out = (float*)d_out;

    float* ws = (float*)d_ws;
    float*          xq_g   = ws;                               // 262144 f32 (dead after kxc)
    float*          xc     = ws + 262144;                      // 262144 f32 (dead after k3f)
    float*          patl   = ws;                               // 524288 f32, ALIASES xq_g+xc
    float*          Cw     = ws + 524288;                      // 262144 f32
    float*          u      = ws + 786432;                      // 262144 f32
    float*          outlin = ws + 1048576;                     // 131072 f32
    float*          bsg    = ws + 1179648;                     // 2048 f32 (1536 used)
    unsigned short* xcb    = (unsigned short*)(ws + 1181696);  // 262144 bf16
    unsigned short* xkb    = (unsigned short*)(ws + 1312768);  // 262144 bf16
    unsigned short* Wsgb   = (unsigned short*)(ws + 1443840);  // 786432 bf16
    unsigned short* W_outb = (unsigned short*)(ws + 1837056);  // 131072 bf16
    unsigned short* ybb    = (unsigned short*)(ws + 1902592);  // 262144 bf16
    // AREA: {xb, Wb, cwb} dead after kxc; reused for C_loc (NC=8, in-place)
    float*          area   = ws + 2033664;                     // 4194304 f32
    unsigned short* xb     = (unsigned short*)area;            // 131072 bf16
    unsigned short* Wb     = (unsigned short*)(area + 65536);  // 262144 bf16
    unsigned short* cwb    = (unsigned short*)(area + 196608); // 786432 bf16
    float*          C_loc  = area;                             // 2*8*512*512 = 4194304 f32

    kcvt       <<<512, 256, 0, stream>>>(x, W_in, conv_w, W_ssm, W_gate, b_ssm,
                                         b_gate, W_out, xb, Wb, cwb, Wsgb, bsg, W_outb);
    k1_mfma    <<<512, 256, 0, stream>>>(xb, Wb, xq_g, xkb);
    kxc_mfma   <<<256, 256, 0, stream>>>(xkb, cwb, xq_g, conv_b, xc, xcb);
    k3f_mfma   <<<256, 256, 0, stream>>>(xcb, Wsgb, bsg, xc, Cw, u);
    k4a_pass1  <<<512, 256, 0, stream>>>(u, A, C_loc);
    k4b_combine<<<512, 256, 0, stream>>>(A, C_loc);
    k4c_pass2  <<<512, 256, 0, stream>>>(u, Cw, A, C_loc, patl);
    k4d_add    <<<512, 256, 0, stream>>>(patl, u, D, ybb);
    k5a_mfma   <<<128, 256, 0, stream>>>(ybb, W_outb, outlin);
    k5b_ln     <<<512, 256, 0, stream>>>(outlin, x, z, ln_g, ln_b, out);
}